// Round 3
// baseline (525.739 us; speedup 1.0000x reference)
//
#include <hip/hip_runtime.h>
#include <hip/hip_fp16.h>
#include <type_traits>

#define NU 100000
#define NI 50000
#define NN 150000          // NU + NI
#define HH 64
#define NE 1200000

#define SCAN_CHUNK 1024
#define NBLK ((NN + SCAN_CHUNK - 1) / SCAN_CHUNK)   // 147

#define LAYER_BLOCKS 1280
#define LAYER_WAVES (LAYER_BLOCKS * 4)   // 5120 waves, grid-resident

// ---------------------------------------------------------------- concat + passthrough
// Writes fp16 gather-source Ah = concat(users, items), plus fp32 passthrough outputs.
__global__ void k_concat(const float4* __restrict__ users, const float4* __restrict__ items,
                         __half2* __restrict__ Ah, float4* __restrict__ out) {
    int i = blockIdx.x * blockDim.x + threadIdx.x;   // over NN*16 float4
    const int TOT = NN * (HH / 4);                   // 2,400,000
    const int UB  = NU * (HH / 4);                   // 1,600,000
    if (i >= TOT) return;
    float4 v;
    if (i < UB) {
        v = users[i];
        out[UB + i] = v;                             // O1 = users_emb passthrough
    } else {
        int j = i - UB;
        v = items[j];
        out[2 * UB + NI * (HH / 4) + j] = v;         // O3 = items_emb passthrough
    }
    Ah[2 * i]     = __halves2half2(__float2half_rn(v.x), __float2half_rn(v.y));
    Ah[2 * i + 1] = __halves2half2(__float2half_rn(v.z), __float2half_rn(v.w));
}

// ---------------------------------------------------------------- degree histogram
// 4 edges/thread: int4 load, 4 independent atomics in flight.
__global__ void k_hist(const int4* __restrict__ dst4, int* __restrict__ counts) {
    int t = blockIdx.x * blockDim.x + threadIdx.x;   // over NE/4
    if (t >= NE / 4) return;
    int4 d = dst4[t];
    atomicAdd(&counts[d.x], 1);
    atomicAdd(&counts[d.y], 1);
    atomicAdd(&counts[d.z], 1);
    atomicAdd(&counts[d.w], 1);
}

// ---------------------------------------------------------------- scan reduce + dinv (fused)
__global__ void k_scan_reduce(const int* __restrict__ counts, int* __restrict__ bsum,
                              float* __restrict__ dinv) {
    __shared__ int sd[256];
    int t = threadIdx.x;
    int base = blockIdx.x * SCAN_CHUNK + t * 4;
    int s = 0;
    if (base + 3 < NN) {
        int4 v = *(const int4*)(counts + base);
        s = v.x + v.y + v.z + v.w;
        dinv[base + 0] = rsqrtf((float)(v.x + 1));
        dinv[base + 1] = rsqrtf((float)(v.y + 1));
        dinv[base + 2] = rsqrtf((float)(v.z + 1));
        dinv[base + 3] = rsqrtf((float)(v.w + 1));
    } else {
        for (int i = 0; i < 4; ++i)
            if (base + i < NN) {
                int c = counts[base + i];
                s += c;
                dinv[base + i] = rsqrtf((float)(c + 1));
            }
    }
    sd[t] = s; __syncthreads();
    for (int off = 128; off > 0; off >>= 1) {
        if (t < off) sd[t] += sd[t + off];
        __syncthreads();
    }
    if (t == 0) bsum[blockIdx.x] = sd[0];
}

__global__ void k_scan_top(int* __restrict__ bsum, int* __restrict__ row_ptr) {
    __shared__ int sd[256];
    int t = threadIdx.x;
    int v = (t < NBLK) ? bsum[t] : 0;
    sd[t] = v; __syncthreads();
    for (int off = 1; off < 256; off <<= 1) {
        int x = (t >= off) ? sd[t - off] : 0;
        __syncthreads();
        sd[t] += x;
        __syncthreads();
    }
    if (t < NBLK) bsum[t] = sd[t] - v;   // exclusive block offsets
    if (t == 0) row_ptr[NN] = NE;
}

__global__ void k_scan_chunks(const int* __restrict__ counts, const int* __restrict__ boff,
                              int* __restrict__ row_ptr) {
    __shared__ int sd[256];
    int t = threadIdx.x;
    int base = blockIdx.x * SCAN_CHUNK + t * 4;
    int c[4];
#pragma unroll
    for (int i = 0; i < 4; ++i) c[i] = (base + i < NN) ? counts[base + i] : 0;
    int tt = c[0] + c[1] + c[2] + c[3];
    sd[t] = tt; __syncthreads();
    for (int off = 1; off < 256; off <<= 1) {
        int x = (t >= off) ? sd[t - off] : 0;
        __syncthreads();
        sd[t] += x;
        __syncthreads();
    }
    int off0 = boff[blockIdx.x] + (sd[t] - tt);
    int run = 0;
#pragma unroll
    for (int i = 0; i < 4; ++i) {
        if (base + i < NN) row_ptr[base + i] = off0 + run;
        run += c[i];
    }
}

// ---------------------------------------------------------------- CSR fill: (src, norm) per slot
// 4 edges/thread: int4 loads, 8 independent dinv gathers, 4 independent atomics,
// 4 independent scatter writes — 4x the memory-level parallelism of 1-edge/thread.
__global__ void k_fill(const int4* __restrict__ src4, const int4* __restrict__ dst4,
                       const float* __restrict__ dinv, const int* __restrict__ row_ptr,
                       int* __restrict__ cursor, int2* __restrict__ colw) {
    int t = blockIdx.x * blockDim.x + threadIdx.x;   // over NE/4
    if (t >= NE / 4) return;
    int4 s = src4[t];
    int4 d = dst4[t];
    float ds0 = dinv[s.x], ds1 = dinv[s.y], ds2 = dinv[s.z], ds3 = dinv[s.w];
    float dd0 = dinv[d.x], dd1 = dinv[d.y], dd2 = dinv[d.z], dd3 = dinv[d.w];
    int p0 = atomicAdd(&cursor[d.x], 1);
    int p1 = atomicAdd(&cursor[d.y], 1);
    int p2 = atomicAdd(&cursor[d.z], 1);
    int p3 = atomicAdd(&cursor[d.w], 1);
    int r0 = row_ptr[d.x], r1 = row_ptr[d.y], r2 = row_ptr[d.z], r3 = row_ptr[d.w];
    colw[r0 + p0] = make_int2(s.x, __float_as_int(ds0 * dd0));
    colw[r1 + p1] = make_int2(s.y, __float_as_int(ds1 * dd1));
    colw[r2 + p2] = make_int2(s.z, __float_as_int(ds2 * dd2));
    colw[r3 + p3] = make_int2(s.w, __float_as_int(ds3 * dd3));
}

// ---------------------------------------------------------------- fused layer:
// out = (A_norm * x) @ W + b      (x fp16; aggregation fp32; matmul fp32)
// Wave-per-node, lane = feature. W column `lane` lives in 64 VGPRs, loaded once
// per wave and amortized over ~30 nodes (grid-resident 5120 waves). Per node,
// the aggregated row is broadcast via unrolled v_readlane (VALU, no LDS) into
// 64 FMAs against the register-resident W column.
// OutT=__half: write next layer's fp16 gather source. OutT=float: split-write
// into d_out's two x slices.
template <typename OutT>
__global__ __launch_bounds__(256) void k_layer(const __half* __restrict__ x,
                                               const float* __restrict__ dinv,
                                               const int* __restrict__ row_ptr,
                                               const int2* __restrict__ colw,
                                               const float* __restrict__ W,
                                               const float* __restrict__ b,
                                               OutT* __restrict__ out_lo,
                                               OutT* __restrict__ out_hi,
                                               int split) {
    int lane = threadIdx.x & 63;
    int wid = blockIdx.x * 4 + (threadIdx.x >> 6);

    float Wcol[HH];
#pragma unroll
    for (int k = 0; k < HH; ++k) Wcol[k] = W[k * HH + lane];
    float bj = b[lane];

    for (int node = wid; node < NN; node += LAYER_WAVES) {
        float dv = dinv[node];
        float acc = dv * dv * __half2float(x[node * HH + lane]);
        int e = row_ptr[node], end = row_ptr[node + 1];
        for (; e + 3 < end; e += 4) {
            int2 c0 = colw[e];
            int2 c1 = colw[e + 1];
            int2 c2 = colw[e + 2];
            int2 c3 = colw[e + 3];
            float v0 = __half2float(x[c0.x * HH + lane]);
            float v1 = __half2float(x[c1.x * HH + lane]);
            float v2 = __half2float(x[c2.x * HH + lane]);
            float v3 = __half2float(x[c3.x * HH + lane]);
            acc += __int_as_float(c0.y) * v0;
            acc += __int_as_float(c1.y) * v1;
            acc += __int_as_float(c2.y) * v2;
            acc += __int_as_float(c3.y) * v3;
        }
        if (e + 1 < end) {
            int2 c0 = colw[e];
            int2 c1 = colw[e + 1];
            float v0 = __half2float(x[c0.x * HH + lane]);
            float v1 = __half2float(x[c1.x * HH + lane]);
            acc += __int_as_float(c0.y) * v0;
            acc += __int_as_float(c1.y) * v1;
            e += 2;
        }
        if (e < end) {
            int2 c = colw[e];
            acc += __int_as_float(c.y) * __half2float(x[c.x * HH + lane]);
        }

        // per-node matmul: out[lane] = b[lane] + sum_k acc_k * W[k][lane]
        float o = bj;
#pragma unroll
        for (int k = 0; k < HH; ++k) {
            float ak = __int_as_float(__builtin_amdgcn_readlane(__float_as_int(acc), k));
            o += ak * Wcol[k];
        }

        if constexpr (std::is_same_v<OutT, __half>) {
            out_lo[(size_t)node * HH + lane] = __float2half_rn(o);
        } else {
            float* dptr = (node < split) ? ((float*)out_lo + (size_t)node * HH)
                                         : ((float*)out_hi + (size_t)(node - split) * HH);
            dptr[lane] = o;
        }
    }
}

// ---------------------------------------------------------------- launch
extern "C" void kernel_launch(void* const* d_in, const int* in_sizes, int n_in,
                              void* d_out, int out_size, void* d_ws, size_t ws_size,
                              hipStream_t stream) {
    const int*   edge  = (const int*)d_in[0];
    const int*   src   = edge;           // edge_index[0]
    const int*   dst   = edge + NE;      // edge_index[1]
    const float* users = (const float*)d_in[1];
    const float* items = (const float*)d_in[2];
    const float* Ws    = (const float*)d_in[3];   // [3][64][64]
    const float* bs    = (const float*)d_in[4];   // [3][64]
    float*       out   = (float*)d_out;

    // workspace carve (~50 MB total)
    char* w = (char*)d_ws;
    __half* Ah0     = (__half*)w; w += (size_t)NN * HH * 2;   // 19.2 MB (gather src, fp16)
    __half* Ah1     = (__half*)w; w += (size_t)NN * HH * 2;   // 19.2 MB (double buffer)
    float*  dinv    = (float*)w;  w += (size_t)NN * 4;
    int*    counts  = (int*)w;    w += (size_t)NN * 4;
    int*    cursor  = (int*)w;    w += (size_t)NN * 4;        // adjacent to counts: one memset
    int*    row_ptr = (int*)w;    w += (size_t)(NN + 1) * 4;
    w += 4;                                                   // 8-byte align
    int*    bsum    = (int*)w;    w += 256 * 4;
    int2*   colw    = (int2*)w;   w += (size_t)NE * 8;        // 9.6 MB
    (void)ws_size; (void)in_sizes; (void)n_in; (void)out_size;

    hipMemsetAsync(counts, 0, (size_t)2 * NN * sizeof(int), stream);  // counts + cursor

    k_concat<<<(NN * (HH / 4) + 255) / 256, 256, 0, stream>>>(
        (const float4*)users, (const float4*)items, (__half2*)Ah0, (float4*)out);

    k_hist<<<(NE / 4 + 255) / 256, 256, 0, stream>>>((const int4*)dst, counts);
    k_scan_reduce<<<NBLK, 256, 0, stream>>>(counts, bsum, dinv);
    k_scan_top<<<1, 256, 0, stream>>>(bsum, row_ptr);
    k_scan_chunks<<<NBLK, 256, 0, stream>>>(counts, bsum, row_ptr);
    k_fill<<<(NE / 4 + 255) / 256, 256, 0, stream>>>(
        (const int4*)src, (const int4*)dst, dinv, row_ptr, cursor, colw);

    // layer 0: Ah0 -> Ah1 ; layer 1: Ah1 -> Ah0 ; layer 2: Ah0 -> d_out (fp32, split)
    k_layer<__half><<<LAYER_BLOCKS, 256, 0, stream>>>(
        Ah0, dinv, row_ptr, colw, Ws + 0 * HH * HH, bs + 0 * HH, Ah1, Ah1, NN);
    k_layer<__half><<<LAYER_BLOCKS, 256, 0, stream>>>(
        Ah1, dinv, row_ptr, colw, Ws + 1 * HH * HH, bs + 1 * HH, Ah0, Ah0, NN);
    k_layer<float><<<LAYER_BLOCKS, 256, 0, stream>>>(
        Ah0, dinv, row_ptr, colw, Ws + 2 * HH * HH, bs + 2 * HH,
        out /* x_users */, out + (size_t)2 * NU * HH /* x_items */, NU);
}

// Round 4
// 480.798 us; speedup vs baseline: 1.0935x; 1.0935x over previous
//
#include <hip/hip_runtime.h>
#include <hip/hip_fp16.h>
#include <type_traits>

#define NU 100000
#define NI 50000
#define NN 150000          // NU + NI (even)
#define HH 64
#define NE 1200000

#define SCAN_CHUNK 1024
#define NBLK ((NN + SCAN_CHUNK - 1) / SCAN_CHUNK)   // 147

// ---------------------------------------------------------------- concat + passthrough
// Writes PRESCALED fp16 gather-source xs = dinv * concat(users, items), plus the
// fp32 passthrough outputs. (norm = dinv[s]*dinv[d] is folded into the operand:
// y[d] = dinv[d] * (xs[d] + sum xs[s]).)
__global__ void k_concat(const float4* __restrict__ users, const float4* __restrict__ items,
                         const float* __restrict__ dinv,
                         __half2* __restrict__ xs, float4* __restrict__ out) {
    int i = blockIdx.x * blockDim.x + threadIdx.x;   // over NN*16 float4
    const int TOT = NN * (HH / 4);                   // 2,400,000
    const int UB  = NU * (HH / 4);                   // 1,600,000
    if (i >= TOT) return;
    float4 v;
    if (i < UB) {
        v = users[i];
        out[UB + i] = v;                             // O1 = users_emb passthrough
    } else {
        int j = i - UB;
        v = items[j];
        out[2 * UB + NI * (HH / 4) + j] = v;         // O3 = items_emb passthrough
    }
    float dv = dinv[i >> 4];                         // node = i/16
    xs[2 * i]     = __halves2half2(__float2half_rn(v.x * dv), __float2half_rn(v.y * dv));
    xs[2 * i + 1] = __halves2half2(__float2half_rn(v.z * dv), __float2half_rn(v.w * dv));
}

// ---------------------------------------------------------------- degree histogram
__global__ void k_hist(const int4* __restrict__ dst4, int* __restrict__ counts) {
    int t = blockIdx.x * blockDim.x + threadIdx.x;   // over NE/4
    if (t >= NE / 4) return;
    int4 d = dst4[t];
    atomicAdd(&counts[d.x], 1);
    atomicAdd(&counts[d.y], 1);
    atomicAdd(&counts[d.z], 1);
    atomicAdd(&counts[d.w], 1);
}

// ---------------------------------------------------------------- scan reduce + dinv (fused)
__global__ void k_scan_reduce(const int* __restrict__ counts, int* __restrict__ bsum,
                              float* __restrict__ dinv) {
    __shared__ int sd[256];
    int t = threadIdx.x;
    int base = blockIdx.x * SCAN_CHUNK + t * 4;
    int s = 0;
    if (base + 3 < NN) {
        int4 v = *(const int4*)(counts + base);
        s = v.x + v.y + v.z + v.w;
        dinv[base + 0] = rsqrtf((float)(v.x + 1));
        dinv[base + 1] = rsqrtf((float)(v.y + 1));
        dinv[base + 2] = rsqrtf((float)(v.z + 1));
        dinv[base + 3] = rsqrtf((float)(v.w + 1));
    } else {
        for (int i = 0; i < 4; ++i)
            if (base + i < NN) {
                int c = counts[base + i];
                s += c;
                dinv[base + i] = rsqrtf((float)(c + 1));
            }
    }
    sd[t] = s; __syncthreads();
    for (int off = 128; off > 0; off >>= 1) {
        if (t < off) sd[t] += sd[t + off];
        __syncthreads();
    }
    if (t == 0) bsum[blockIdx.x] = sd[0];
}

__global__ void k_scan_top(int* __restrict__ bsum, int* __restrict__ row_ptr) {
    __shared__ int sd[256];
    int t = threadIdx.x;
    int v = (t < NBLK) ? bsum[t] : 0;
    sd[t] = v; __syncthreads();
    for (int off = 1; off < 256; off <<= 1) {
        int x = (t >= off) ? sd[t - off] : 0;
        __syncthreads();
        sd[t] += x;
        __syncthreads();
    }
    if (t < NBLK) bsum[t] = sd[t] - v;   // exclusive block offsets
    if (t == 0) row_ptr[NN] = NE;
}

__global__ void k_scan_chunks(const int* __restrict__ counts, const int* __restrict__ boff,
                              int* __restrict__ row_ptr) {
    __shared__ int sd[256];
    int t = threadIdx.x;
    int base = blockIdx.x * SCAN_CHUNK + t * 4;
    int c[4];
#pragma unroll
    for (int i = 0; i < 4; ++i) c[i] = (base + i < NN) ? counts[base + i] : 0;
    int tt = c[0] + c[1] + c[2] + c[3];
    sd[t] = tt; __syncthreads();
    for (int off = 1; off < 256; off <<= 1) {
        int x = (t >= off) ? sd[t - off] : 0;
        __syncthreads();
        sd[t] += x;
        __syncthreads();
    }
    int off0 = boff[blockIdx.x] + (sd[t] - tt);
    int run = 0;
#pragma unroll
    for (int i = 0; i < 4; ++i) {
        if (base + i < NN) row_ptr[base + i] = off0 + run;
        run += c[i];
    }
}

// ---------------------------------------------------------------- CSR fill: src index per slot
// Weight is folded into the prescaled operand, so a slot is 4 B (was 8 B):
// halves the random-scatter write traffic. 4 edges/thread for MLP.
__global__ void k_fill(const int4* __restrict__ src4, const int4* __restrict__ dst4,
                       const int* __restrict__ row_ptr,
                       int* __restrict__ cursor, int* __restrict__ col) {
    int t = blockIdx.x * blockDim.x + threadIdx.x;   // over NE/4
    if (t >= NE / 4) return;
    int4 s = src4[t];
    int4 d = dst4[t];
    int p0 = atomicAdd(&cursor[d.x], 1);
    int p1 = atomicAdd(&cursor[d.y], 1);
    int p2 = atomicAdd(&cursor[d.z], 1);
    int p3 = atomicAdd(&cursor[d.w], 1);
    int r0 = row_ptr[d.x], r1 = row_ptr[d.y], r2 = row_ptr[d.z], r3 = row_ptr[d.w];
    col[r0 + p0] = s.x;
    col[r1 + p1] = s.y;
    col[r2 + p2] = s.z;
    col[r3 + p3] = s.w;
}

// ---------------------------------------------------------------- aggregation
// y[n] = fp16( dinv[n] * (xs[n] + sum_{s in N(n)} xs[s]) )
// TWO nodes per wave with interleaved unroll-4 edge loops: 8 independent
// gather chains in flight (vs 4 single-node) — attacks gather latency.
#define G1(c) __half2float(x[(size_t)(c) * HH + lane])
__global__ __launch_bounds__(256) void k_aggregate(const __half* __restrict__ x,
                                                   __half* __restrict__ y,
                                                   const float* __restrict__ dinv,
                                                   const int* __restrict__ row_ptr,
                                                   const int* __restrict__ col) {
    int lane = threadIdx.x & 63;
    int wave = blockIdx.x * 4 + (threadIdx.x >> 6);
    int na = wave * 2;
    if (na >= NN) return;
    int nb = na + 1;                                  // NN even: always valid

    float acca = G1(na);                              // self term (prescaled)
    float accb = G1(nb);
    int ea = row_ptr[na], enda = row_ptr[na + 1];
    int eb = enda,        endb = row_ptr[nb + 1];     // rows adjacent

    while (ea + 4 <= enda && eb + 4 <= endb) {
        int a0 = col[ea], a1 = col[ea + 1], a2 = col[ea + 2], a3 = col[ea + 3];
        int b0 = col[eb], b1 = col[eb + 1], b2 = col[eb + 2], b3 = col[eb + 3];
        float va0 = G1(a0), va1 = G1(a1), va2 = G1(a2), va3 = G1(a3);
        float vb0 = G1(b0), vb1 = G1(b1), vb2 = G1(b2), vb3 = G1(b3);
        acca += (va0 + va1) + (va2 + va3);
        accb += (vb0 + vb1) + (vb2 + vb3);
        ea += 4; eb += 4;
    }
    // drain a
    for (; ea + 4 <= enda; ea += 4) {
        int c0 = col[ea], c1 = col[ea + 1], c2 = col[ea + 2], c3 = col[ea + 3];
        acca += (G1(c0) + G1(c1)) + (G1(c2) + G1(c3));
    }
    if (ea + 2 <= enda) {
        int c0 = col[ea], c1 = col[ea + 1];
        acca += G1(c0) + G1(c1);
        ea += 2;
    }
    if (ea < enda) acca += G1(col[ea]);
    // drain b
    for (; eb + 4 <= endb; eb += 4) {
        int c0 = col[eb], c1 = col[eb + 1], c2 = col[eb + 2], c3 = col[eb + 3];
        accb += (G1(c0) + G1(c1)) + (G1(c2) + G1(c3));
    }
    if (eb + 2 <= endb) {
        int c0 = col[eb], c1 = col[eb + 1];
        accb += G1(c0) + G1(c1);
        eb += 2;
    }
    if (eb < endb) accb += G1(col[eb]);

    y[(size_t)na * HH + lane] = __float2half_rn(dinv[na] * acca);
    y[(size_t)nb * HH + lane] = __float2half_rn(dinv[nb] * accb);
}
#undef G1

// ---------------------------------------------------------------- GEMM: out = y @ W + b
// y is fp16 (aggregate output). 256 threads, 128 rows/block, 4x8 thread tile,
// W + y-tile (converted to fp32) in LDS.
// OutT=__half: writes NEXT layer's prescaled gather source fp16(dinv*(yW+b)).
// OutT=float:  final layer — split-write fp32 into d_out's two x slices.
#define GR 128
#define XSS 65   // +1 pad: conflict-free scalar broadcasts
template <typename OutT>
__global__ __launch_bounds__(256) void k_gemm(const __half* __restrict__ y,
                                              const float* __restrict__ W,
                                              const float* __restrict__ b,
                                              const float* __restrict__ dinv,
                                              OutT* __restrict__ out_lo,
                                              OutT* __restrict__ out_hi,
                                              int split) {
    __shared__ float xs[GR * XSS];   // 33.3 KB
    __shared__ float ws[HH * HH];    // 16 KB
    int t = threadIdx.x;
    int rowBase = blockIdx.x * GR;

    {   // stage W: 1024 float4 / 256 threads
        const float4* W4 = (const float4*)W;
        float4* ws4 = (float4*)ws;
#pragma unroll
        for (int i = 0; i < 4; ++i) ws4[i * 256 + t] = W4[i * 256 + t];
    }
    // stage y tile: 1024 8-half chunks / 256 threads, fp16 -> fp32 into LDS
#pragma unroll
    for (int it = 0; it < 4; ++it) {
        int g = it * 256 + t;        // 0..1023
        int r = g >> 3;
        int c0 = (g & 7) * 8;
        int row = rowBase + r;
        if (row < NN) {
            int4 raw = *(const int4*)(y + (size_t)row * HH + c0);   // 8 halves
            __half2 h0 = *(__half2*)&raw.x, h1 = *(__half2*)&raw.y;
            __half2 h2 = *(__half2*)&raw.z, h3 = *(__half2*)&raw.w;
            float2 f0 = __half22float2(h0), f1 = __half22float2(h1);
            float2 f2 = __half22float2(h2), f3 = __half22float2(h3);
            float* dp = xs + r * XSS + c0;
            dp[0] = f0.x; dp[1] = f0.y; dp[2] = f1.x; dp[3] = f1.y;
            dp[4] = f2.x; dp[5] = f2.y; dp[6] = f3.x; dp[7] = f3.y;
        }
    }
    __syncthreads();

    int tx = t & 7;        // 8 col-groups of 8
    int ty = t >> 3;       // 32 row-groups of 4
    int j0 = tx * 8;
    int r0 = ty * 4;

    float acc[4][8];
#pragma unroll
    for (int i = 0; i < 4; ++i)
#pragma unroll
        for (int j = 0; j < 8; ++j) acc[i][j] = 0.f;

    for (int k = 0; k < HH; ++k) {
        float4 w0 = *(const float4*)(ws + k * HH + j0);
        float4 w1 = *(const float4*)(ws + k * HH + j0 + 4);
        float wv[8] = {w0.x, w0.y, w0.z, w0.w, w1.x, w1.y, w1.z, w1.w};
#pragma unroll
        for (int i = 0; i < 4; ++i) {
            float xv = xs[(r0 + i) * XSS + k];
#pragma unroll
            for (int j = 0; j < 8; ++j) acc[i][j] += xv * wv[j];
        }
    }

    float bj[8];
#pragma unroll
    for (int j = 0; j < 8; ++j) bj[j] = b[j0 + j];

#pragma unroll
    for (int i = 0; i < 4; ++i) {
        int r = rowBase + r0 + i;
        if (r >= NN) continue;
        if constexpr (std::is_same_v<OutT, float>) {
            float4 o0 = make_float4(acc[i][0] + bj[0], acc[i][1] + bj[1],
                                    acc[i][2] + bj[2], acc[i][3] + bj[3]);
            float4 o1 = make_float4(acc[i][4] + bj[4], acc[i][5] + bj[5],
                                    acc[i][6] + bj[6], acc[i][7] + bj[7]);
            float* d = (r < split) ? ((float*)out_lo + (size_t)r * HH)
                                   : ((float*)out_hi + (size_t)(r - split) * HH);
            *(float4*)(d + j0) = o0;
            *(float4*)(d + j0 + 4) = o1;
        } else {
            float dv = dinv[r];   // prescale for next layer's gather source
            __half2 h[4];
#pragma unroll
            for (int j = 0; j < 4; ++j)
                h[j] = __halves2half2(
                    __float2half_rn((acc[i][2 * j]     + bj[2 * j])     * dv),
                    __float2half_rn((acc[i][2 * j + 1] + bj[2 * j + 1]) * dv));
            __half* d = (__half*)out_lo + (size_t)r * HH + j0;
            *(int4*)d = *(int4*)h;   // 16-B store
        }
    }
}

// ---------------------------------------------------------------- launch
extern "C" void kernel_launch(void* const* d_in, const int* in_sizes, int n_in,
                              void* d_out, int out_size, void* d_ws, size_t ws_size,
                              hipStream_t stream) {
    const int*   edge  = (const int*)d_in[0];
    const int*   src   = edge;           // edge_index[0]
    const int*   dst   = edge + NE;      // edge_index[1]
    const float* users = (const float*)d_in[1];
    const float* items = (const float*)d_in[2];
    const float* Ws    = (const float*)d_in[3];   // [3][64][64]
    const float* bs    = (const float*)d_in[4];   // [3][64]
    float*       out   = (float*)d_out;

    // workspace carve (~45 MB total)
    char* w = (char*)d_ws;
    __half* Xs0     = (__half*)w; w += (size_t)NN * HH * 2;   // 19.2 MB prescaled src
    __half* Xs1     = (__half*)w; w += (size_t)NN * HH * 2;   // 19.2 MB (dbl buffer / y)
    float*  dinv    = (float*)w;  w += (size_t)NN * 4;
    int*    counts  = (int*)w;    w += (size_t)NN * 4;
    int*    cursor  = (int*)w;    w += (size_t)NN * 4;        // adjacent: one memset
    int*    row_ptr = (int*)w;    w += (size_t)(NN + 1) * 4;
    w += 4;                                                   // realign
    int*    bsum    = (int*)w;    w += 256 * 4;
    int*    col     = (int*)w;    w += (size_t)NE * 4;        // 4.8 MB
    (void)ws_size; (void)in_sizes; (void)n_in; (void)out_size;

    hipMemsetAsync(counts, 0, (size_t)2 * NN * sizeof(int), stream);  // counts + cursor

    k_hist<<<(NE / 4 + 255) / 256, 256, 0, stream>>>((const int4*)dst, counts);
    k_scan_reduce<<<NBLK, 256, 0, stream>>>(counts, bsum, dinv);
    k_concat<<<(NN * (HH / 4) + 255) / 256, 256, 0, stream>>>(
        (const float4*)users, (const float4*)items, dinv, (__half2*)Xs0, (float4*)out);
    k_scan_top<<<1, 256, 0, stream>>>(bsum, row_ptr);
    k_scan_chunks<<<NBLK, 256, 0, stream>>>(counts, bsum, row_ptr);
    k_fill<<<(NE / 4 + 255) / 256, 256, 0, stream>>>(
        (const int4*)src, (const int4*)dst, row_ptr, cursor, col);

    // per layer: aggregate (Xs -> y fp16), gemm (y -> next Xs / final out)
    const int AGG_BLOCKS  = NN / 8;                    // 2 nodes/wave, 4 waves/block
    const int GEMM_BLOCKS = (NN + GR - 1) / GR;

    k_aggregate<<<AGG_BLOCKS, 256, 0, stream>>>(Xs0, Xs1, dinv, row_ptr, col);
    k_gemm<__half><<<GEMM_BLOCKS, 256, 0, stream>>>(
        Xs1, Ws + 0 * HH * HH, bs + 0 * HH, dinv, Xs0, Xs0, NN);
    k_aggregate<<<AGG_BLOCKS, 256, 0, stream>>>(Xs0, Xs1, dinv, row_ptr, col);
    k_gemm<__half><<<GEMM_BLOCKS, 256, 0, stream>>>(
        Xs1, Ws + 1 * HH * HH, bs + 1 * HH, dinv, Xs0, Xs0, NN);
    k_aggregate<<<AGG_BLOCKS, 256, 0, stream>>>(Xs0, Xs1, dinv, row_ptr, col);
    k_gemm<float><<<GEMM_BLOCKS, 256, 0, stream>>>(
        Xs1, Ws + 2 * HH * HH, bs + 2 * HH, dinv,
        out /* x_users */, out + (size_t)2 * NU * HH /* x_items */, NU);
}

// Round 5
// 415.075 us; speedup vs baseline: 1.2666x; 1.1583x over previous
//
#include <hip/hip_runtime.h>
#include <hip/hip_fp16.h>
#include <type_traits>

#define NU 100000
#define NI 50000
#define NN 150000          // NU + NI (even)
#define HH 64
#define NE 1200000

#define SCAN_CHUNK 1024
#define NBLK ((NN + SCAN_CHUNK - 1) / SCAN_CHUNK)   // 147

// ---------------------------------------------------------------- concat + passthrough
// Writes PRESCALED fp16 gather-source xs = dinv * concat(users, items), plus the
// fp32 passthrough outputs. (norm = dinv[s]*dinv[d] is folded into the operand:
// y[d] = dinv[d] * (xs[d] + sum xs[s]).)
__global__ void k_concat(const float4* __restrict__ users, const float4* __restrict__ items,
                         const float* __restrict__ dinv,
                         __half2* __restrict__ xs, float4* __restrict__ out) {
    int i = blockIdx.x * blockDim.x + threadIdx.x;   // over NN*16 float4
    const int TOT = NN * (HH / 4);                   // 2,400,000
    const int UB  = NU * (HH / 4);                   // 1,600,000
    if (i >= TOT) return;
    float4 v;
    if (i < UB) {
        v = users[i];
        out[UB + i] = v;                             // O1 = users_emb passthrough
    } else {
        int j = i - UB;
        v = items[j];
        out[2 * UB + NI * (HH / 4) + j] = v;         // O3 = items_emb passthrough
    }
    float dv = dinv[i >> 4];                         // node = i/16
    xs[2 * i]     = __halves2half2(__float2half_rn(v.x * dv), __float2half_rn(v.y * dv));
    xs[2 * i + 1] = __halves2half2(__float2half_rn(v.z * dv), __float2half_rn(v.w * dv));
}

// ---------------------------------------------------------------- degree histogram + rank
// rank[e] = this edge's ordinal among same-dst edges (atomicAdd return value).
// Any ordering is valid (the aggregation sum commutes). Sequential int4 rank
// store; this removes ALL atomics from the CSR-fill scatter phase.
__global__ void k_rank(const int4* __restrict__ dst4, int* __restrict__ counts,
                       int4* __restrict__ rank4) {
    int t = blockIdx.x * blockDim.x + threadIdx.x;   // over NE/4
    if (t >= NE / 4) return;
    int4 d = dst4[t];
    int4 r;
    r.x = atomicAdd(&counts[d.x], 1);
    r.y = atomicAdd(&counts[d.y], 1);
    r.z = atomicAdd(&counts[d.z], 1);
    r.w = atomicAdd(&counts[d.w], 1);
    rank4[t] = r;
}

// ---------------------------------------------------------------- scan reduce + dinv (fused)
__global__ void k_scan_reduce(const int* __restrict__ counts, int* __restrict__ bsum,
                              float* __restrict__ dinv) {
    __shared__ int sd[256];
    int t = threadIdx.x;
    int base = blockIdx.x * SCAN_CHUNK + t * 4;
    int s = 0;
    if (base + 3 < NN) {
        int4 v = *(const int4*)(counts + base);
        s = v.x + v.y + v.z + v.w;
        dinv[base + 0] = rsqrtf((float)(v.x + 1));
        dinv[base + 1] = rsqrtf((float)(v.y + 1));
        dinv[base + 2] = rsqrtf((float)(v.z + 1));
        dinv[base + 3] = rsqrtf((float)(v.w + 1));
    } else {
        for (int i = 0; i < 4; ++i)
            if (base + i < NN) {
                int c = counts[base + i];
                s += c;
                dinv[base + i] = rsqrtf((float)(c + 1));
            }
    }
    sd[t] = s; __syncthreads();
    for (int off = 128; off > 0; off >>= 1) {
        if (t < off) sd[t] += sd[t + off];
        __syncthreads();
    }
    if (t == 0) bsum[blockIdx.x] = sd[0];
}

__global__ void k_scan_top(int* __restrict__ bsum, int* __restrict__ row_ptr) {
    __shared__ int sd[256];
    int t = threadIdx.x;
    int v = (t < NBLK) ? bsum[t] : 0;
    sd[t] = v; __syncthreads();
    for (int off = 1; off < 256; off <<= 1) {
        int x = (t >= off) ? sd[t - off] : 0;
        __syncthreads();
        sd[t] += x;
        __syncthreads();
    }
    if (t < NBLK) bsum[t] = sd[t] - v;   // exclusive block offsets
    if (t == 0) row_ptr[NN] = NE;
}

__global__ void k_scan_chunks(const int* __restrict__ counts, const int* __restrict__ boff,
                              int* __restrict__ row_ptr) {
    __shared__ int sd[256];
    int t = threadIdx.x;
    int base = blockIdx.x * SCAN_CHUNK + t * 4;
    int c[4];
#pragma unroll
    for (int i = 0; i < 4; ++i) c[i] = (base + i < NN) ? counts[base + i] : 0;
    int tt = c[0] + c[1] + c[2] + c[3];
    sd[t] = tt; __syncthreads();
    for (int off = 1; off < 256; off <<= 1) {
        int x = (t >= off) ? sd[t - off] : 0;
        __syncthreads();
        sd[t] += x;
        __syncthreads();
    }
    int off0 = boff[blockIdx.x] + (sd[t] - tt);
    int run = 0;
#pragma unroll
    for (int i = 0; i < 4; ++i) {
        if (base + i < NN) row_ptr[base + i] = off0 + run;
        run += c[i];
    }
}

// ---------------------------------------------------------------- CSR fill (atomic-free)
// col[row_ptr[dst] + rank] = src. 8 edges/thread: all loads sequential except
// the L2-resident row_ptr gather (600 KB); 8 fully independent scatter stores
// in flight — no atomic round-trip anywhere in the chain.
__global__ void k_fill(const int4* __restrict__ src4, const int4* __restrict__ dst4,
                       const int4* __restrict__ rank4, const int* __restrict__ row_ptr,
                       int* __restrict__ col) {
    int t = blockIdx.x * blockDim.x + threadIdx.x;   // over NE/8
    if (t >= NE / 8) return;
    int4 s0 = src4[2 * t],  s1 = src4[2 * t + 1];
    int4 d0 = dst4[2 * t],  d1 = dst4[2 * t + 1];
    int4 r0 = rank4[2 * t], r1 = rank4[2 * t + 1];
    int p0 = row_ptr[d0.x], p1 = row_ptr[d0.y], p2 = row_ptr[d0.z], p3 = row_ptr[d0.w];
    int p4 = row_ptr[d1.x], p5 = row_ptr[d1.y], p6 = row_ptr[d1.z], p7 = row_ptr[d1.w];
    col[p0 + r0.x] = s0.x;
    col[p1 + r0.y] = s0.y;
    col[p2 + r0.z] = s0.z;
    col[p3 + r0.w] = s0.w;
    col[p4 + r1.x] = s1.x;
    col[p5 + r1.y] = s1.y;
    col[p6 + r1.z] = s1.z;
    col[p7 + r1.w] = s1.w;
}

// ---------------------------------------------------------------- aggregation
// y[n] = fp16( dinv[n] * (xs[n] + sum_{s in N(n)} xs[s]) )
// TWO nodes per wave with interleaved unroll-4 edge loops: 8 independent
// gather chains in flight.
#define G1(c) __half2float(x[(size_t)(c) * HH + lane])
__global__ __launch_bounds__(256) void k_aggregate(const __half* __restrict__ x,
                                                   __half* __restrict__ y,
                                                   const float* __restrict__ dinv,
                                                   const int* __restrict__ row_ptr,
                                                   const int* __restrict__ col) {
    int lane = threadIdx.x & 63;
    int wave = blockIdx.x * 4 + (threadIdx.x >> 6);
    int na = wave * 2;
    if (na >= NN) return;
    int nb = na + 1;                                  // NN even: always valid

    float acca = G1(na);                              // self term (prescaled)
    float accb = G1(nb);
    int ea = row_ptr[na], enda = row_ptr[na + 1];
    int eb = enda,        endb = row_ptr[nb + 1];     // rows adjacent

    while (ea + 4 <= enda && eb + 4 <= endb) {
        int a0 = col[ea], a1 = col[ea + 1], a2 = col[ea + 2], a3 = col[ea + 3];
        int b0 = col[eb], b1 = col[eb + 1], b2 = col[eb + 2], b3 = col[eb + 3];
        float va0 = G1(a0), va1 = G1(a1), va2 = G1(a2), va3 = G1(a3);
        float vb0 = G1(b0), vb1 = G1(b1), vb2 = G1(b2), vb3 = G1(b3);
        acca += (va0 + va1) + (va2 + va3);
        accb += (vb0 + vb1) + (vb2 + vb3);
        ea += 4; eb += 4;
    }
    // drain a
    for (; ea + 4 <= enda; ea += 4) {
        int c0 = col[ea], c1 = col[ea + 1], c2 = col[ea + 2], c3 = col[ea + 3];
        acca += (G1(c0) + G1(c1)) + (G1(c2) + G1(c3));
    }
    if (ea + 2 <= enda) {
        int c0 = col[ea], c1 = col[ea + 1];
        acca += G1(c0) + G1(c1);
        ea += 2;
    }
    if (ea < enda) acca += G1(col[ea]);
    // drain b
    for (; eb + 4 <= endb; eb += 4) {
        int c0 = col[eb], c1 = col[eb + 1], c2 = col[eb + 2], c3 = col[eb + 3];
        accb += (G1(c0) + G1(c1)) + (G1(c2) + G1(c3));
    }
    if (eb + 2 <= endb) {
        int c0 = col[eb], c1 = col[eb + 1];
        accb += G1(c0) + G1(c1);
        eb += 2;
    }
    if (eb < endb) accb += G1(col[eb]);

    y[(size_t)na * HH + lane] = __float2half_rn(dinv[na] * acca);
    y[(size_t)nb * HH + lane] = __float2half_rn(dinv[nb] * accb);
}
#undef G1

// ---------------------------------------------------------------- GEMM: out = y @ W + b
// y is fp16 (aggregate output). 256 threads, 128 rows/block, 4x8 thread tile,
// W + y-tile (converted to fp32) in LDS.
// OutT=__half: writes NEXT layer's prescaled gather source fp16(dinv*(yW+b)).
// OutT=float:  final layer — split-write fp32 into d_out's two x slices.
#define GR 128
#define XSS 65   // +1 pad: conflict-free scalar broadcasts
template <typename OutT>
__global__ __launch_bounds__(256) void k_gemm(const __half* __restrict__ y,
                                              const float* __restrict__ W,
                                              const float* __restrict__ b,
                                              const float* __restrict__ dinv,
                                              OutT* __restrict__ out_lo,
                                              OutT* __restrict__ out_hi,
                                              int split) {
    __shared__ float xs[GR * XSS];   // 33.3 KB
    __shared__ float ws[HH * HH];    // 16 KB
    int t = threadIdx.x;
    int rowBase = blockIdx.x * GR;

    {   // stage W: 1024 float4 / 256 threads
        const float4* W4 = (const float4*)W;
        float4* ws4 = (float4*)ws;
#pragma unroll
        for (int i = 0; i < 4; ++i) ws4[i * 256 + t] = W4[i * 256 + t];
    }
    // stage y tile: 1024 8-half chunks / 256 threads, fp16 -> fp32 into LDS
#pragma unroll
    for (int it = 0; it < 4; ++it) {
        int g = it * 256 + t;        // 0..1023
        int r = g >> 3;
        int c0 = (g & 7) * 8;
        int row = rowBase + r;
        if (row < NN) {
            int4 raw = *(const int4*)(y + (size_t)row * HH + c0);   // 8 halves
            __half2 h0 = *(__half2*)&raw.x, h1 = *(__half2*)&raw.y;
            __half2 h2 = *(__half2*)&raw.z, h3 = *(__half2*)&raw.w;
            float2 f0 = __half22float2(h0), f1 = __half22float2(h1);
            float2 f2 = __half22float2(h2), f3 = __half22float2(h3);
            float* dp = xs + r * XSS + c0;
            dp[0] = f0.x; dp[1] = f0.y; dp[2] = f1.x; dp[3] = f1.y;
            dp[4] = f2.x; dp[5] = f2.y; dp[6] = f3.x; dp[7] = f3.y;
        }
    }
    __syncthreads();

    int tx = t & 7;        // 8 col-groups of 8
    int ty = t >> 3;       // 32 row-groups of 4
    int j0 = tx * 8;
    int r0 = ty * 4;

    float acc[4][8];
#pragma unroll
    for (int i = 0; i < 4; ++i)
#pragma unroll
        for (int j = 0; j < 8; ++j) acc[i][j] = 0.f;

    for (int k = 0; k < HH; ++k) {
        float4 w0 = *(const float4*)(ws + k * HH + j0);
        float4 w1 = *(const float4*)(ws + k * HH + j0 + 4);
        float wv[8] = {w0.x, w0.y, w0.z, w0.w, w1.x, w1.y, w1.z, w1.w};
#pragma unroll
        for (int i = 0; i < 4; ++i) {
            float xv = xs[(r0 + i) * XSS + k];
#pragma unroll
            for (int j = 0; j < 8; ++j) acc[i][j] += xv * wv[j];
        }
    }

    float bj[8];
#pragma unroll
    for (int j = 0; j < 8; ++j) bj[j] = b[j0 + j];

#pragma unroll
    for (int i = 0; i < 4; ++i) {
        int r = rowBase + r0 + i;
        if (r >= NN) continue;
        if constexpr (std::is_same_v<OutT, float>) {
            float4 o0 = make_float4(acc[i][0] + bj[0], acc[i][1] + bj[1],
                                    acc[i][2] + bj[2], acc[i][3] + bj[3]);
            float4 o1 = make_float4(acc[i][4] + bj[4], acc[i][5] + bj[5],
                                    acc[i][6] + bj[6], acc[i][7] + bj[7]);
            float* d = (r < split) ? ((float*)out_lo + (size_t)r * HH)
                                   : ((float*)out_hi + (size_t)(r - split) * HH);
            *(float4*)(d + j0) = o0;
            *(float4*)(d + j0 + 4) = o1;
        } else {
            float dv = dinv[r];   // prescale for next layer's gather source
            __half2 h[4];
#pragma unroll
            for (int j = 0; j < 4; ++j)
                h[j] = __halves2half2(
                    __float2half_rn((acc[i][2 * j]     + bj[2 * j])     * dv),
                    __float2half_rn((acc[i][2 * j + 1] + bj[2 * j + 1]) * dv));
            __half* d = (__half*)out_lo + (size_t)r * HH + j0;
            *(int4*)d = *(int4*)h;   // 16-B store
        }
    }
}

// ---------------------------------------------------------------- launch
extern "C" void kernel_launch(void* const* d_in, const int* in_sizes, int n_in,
                              void* d_out, int out_size, void* d_ws, size_t ws_size,
                              hipStream_t stream) {
    const int*   edge  = (const int*)d_in[0];
    const int*   src   = edge;           // edge_index[0]
    const int*   dst   = edge + NE;      // edge_index[1]
    const float* users = (const float*)d_in[1];
    const float* items = (const float*)d_in[2];
    const float* Ws    = (const float*)d_in[3];   // [3][64][64]
    const float* bs    = (const float*)d_in[4];   // [3][64]
    float*       out   = (float*)d_out;

    // workspace carve (~51 MB total)
    char* w = (char*)d_ws;
    __half* Xs0     = (__half*)w; w += (size_t)NN * HH * 2;   // 19.2 MB prescaled src
    __half* Xs1     = (__half*)w; w += (size_t)NN * HH * 2;   // 19.2 MB (dbl buffer / y)
    float*  dinv    = (float*)w;  w += (size_t)NN * 4;
    int*    counts  = (int*)w;    w += (size_t)NN * 4;
    int*    row_ptr = (int*)w;    w += (size_t)(NN + 1) * 4;
    w += 4;                                                   // realign to 8
    int*    bsum    = (int*)w;    w += 256 * 4;
    int*    col     = (int*)w;    w += (size_t)NE * 4;        // 4.8 MB
    int*    rank    = (int*)w;    w += (size_t)NE * 4;        // 4.8 MB
    (void)ws_size; (void)in_sizes; (void)n_in; (void)out_size;

    hipMemsetAsync(counts, 0, (size_t)NN * sizeof(int), stream);

    k_rank<<<(NE / 4 + 255) / 256, 256, 0, stream>>>((const int4*)dst, counts, (int4*)rank);
    k_scan_reduce<<<NBLK, 256, 0, stream>>>(counts, bsum, dinv);
    k_concat<<<(NN * (HH / 4) + 255) / 256, 256, 0, stream>>>(
        (const float4*)users, (const float4*)items, dinv, (__half2*)Xs0, (float4*)out);
    k_scan_top<<<1, 256, 0, stream>>>(bsum, row_ptr);
    k_scan_chunks<<<NBLK, 256, 0, stream>>>(counts, bsum, row_ptr);
    k_fill<<<(NE / 8 + 255) / 256, 256, 0, stream>>>(
        (const int4*)src, (const int4*)dst, (const int4*)rank, row_ptr, col);

    // per layer: aggregate (Xs -> y fp16), gemm (y -> next Xs / final out)
    const int AGG_BLOCKS  = NN / 8;                    // 2 nodes/wave, 4 waves/block
    const int GEMM_BLOCKS = (NN + GR - 1) / GR;

    k_aggregate<<<AGG_BLOCKS, 256, 0, stream>>>(Xs0, Xs1, dinv, row_ptr, col);
    k_gemm<__half><<<GEMM_BLOCKS, 256, 0, stream>>>(
        Xs1, Ws + 0 * HH * HH, bs + 0 * HH, dinv, Xs0, Xs0, NN);
    k_aggregate<<<AGG_BLOCKS, 256, 0, stream>>>(Xs0, Xs1, dinv, row_ptr, col);
    k_gemm<__half><<<GEMM_BLOCKS, 256, 0, stream>>>(
        Xs1, Ws + 1 * HH * HH, bs + 1 * HH, dinv, Xs0, Xs0, NN);
    k_aggregate<<<AGG_BLOCKS, 256, 0, stream>>>(Xs0, Xs1, dinv, row_ptr, col);
    k_gemm<float><<<GEMM_BLOCKS, 256, 0, stream>>>(
        Xs1, Ws + 2 * HH * HH, bs + 2 * HH, dinv,
        out /* x_users */, out + (size_t)2 * NU * HH /* x_items */, NU);
}

// Round 6
// 414.551 us; speedup vs baseline: 1.2682x; 1.0013x over previous
//
#include <hip/hip_runtime.h>
#include <hip/hip_fp16.h>
#include <type_traits>

#define NU 100000
#define NI 50000
#define NN 150000          // NU + NI (even)
#define HH 64
#define NE 1200000

#define SCAN_CHUNK 1024
#define NBLK ((NN + SCAN_CHUNK - 1) / SCAN_CHUNK)   // 147

// ---------------------------------------------------------------- concat + passthrough
// Writes PRESCALED fp16 gather-source xs = dinv * concat(users, items), plus the
// fp32 passthrough outputs. (norm = dinv[s]*dinv[d] is folded into the operand:
// y[d] = dinv[d] * (xs[d] + sum xs[s]).)
__global__ void k_concat(const float4* __restrict__ users, const float4* __restrict__ items,
                         const float* __restrict__ dinv,
                         __half2* __restrict__ xs, float4* __restrict__ out) {
    int i = blockIdx.x * blockDim.x + threadIdx.x;   // over NN*16 float4
    const int TOT = NN * (HH / 4);                   // 2,400,000
    const int UB  = NU * (HH / 4);                   // 1,600,000
    if (i >= TOT) return;
    float4 v;
    if (i < UB) {
        v = users[i];
        out[UB + i] = v;                             // O1 = users_emb passthrough
    } else {
        int j = i - UB;
        v = items[j];
        out[2 * UB + NI * (HH / 4) + j] = v;         // O3 = items_emb passthrough
    }
    float dv = dinv[i >> 4];                         // node = i/16
    xs[2 * i]     = __halves2half2(__float2half_rn(v.x * dv), __float2half_rn(v.y * dv));
    xs[2 * i + 1] = __halves2half2(__float2half_rn(v.z * dv), __float2half_rn(v.w * dv));
}

// ---------------------------------------------------------------- degree histogram + rank
// rank[e] = this edge's ordinal among same-dst edges (atomicAdd return value).
__global__ void k_rank(const int4* __restrict__ dst4, int* __restrict__ counts,
                       int4* __restrict__ rank4) {
    int t = blockIdx.x * blockDim.x + threadIdx.x;   // over NE/4
    if (t >= NE / 4) return;
    int4 d = dst4[t];
    int4 r;
    r.x = atomicAdd(&counts[d.x], 1);
    r.y = atomicAdd(&counts[d.y], 1);
    r.z = atomicAdd(&counts[d.z], 1);
    r.w = atomicAdd(&counts[d.w], 1);
    rank4[t] = r;
}

// ---------------------------------------------------------------- scan reduce + dinv (fused)
__global__ void k_scan_reduce(const int* __restrict__ counts, int* __restrict__ bsum,
                              float* __restrict__ dinv) {
    __shared__ int sd[256];
    int t = threadIdx.x;
    int base = blockIdx.x * SCAN_CHUNK + t * 4;
    int s = 0;
    if (base + 3 < NN) {
        int4 v = *(const int4*)(counts + base);
        s = v.x + v.y + v.z + v.w;
        dinv[base + 0] = rsqrtf((float)(v.x + 1));
        dinv[base + 1] = rsqrtf((float)(v.y + 1));
        dinv[base + 2] = rsqrtf((float)(v.z + 1));
        dinv[base + 3] = rsqrtf((float)(v.w + 1));
    } else {
        for (int i = 0; i < 4; ++i)
            if (base + i < NN) {
                int c = counts[base + i];
                s += c;
                dinv[base + i] = rsqrtf((float)(c + 1));
            }
    }
    sd[t] = s; __syncthreads();
    for (int off = 128; off > 0; off >>= 1) {
        if (t < off) sd[t] += sd[t + off];
        __syncthreads();
    }
    if (t == 0) bsum[blockIdx.x] = sd[0];
}

__global__ void k_scan_top(int* __restrict__ bsum, int* __restrict__ row_ptr) {
    __shared__ int sd[256];
    int t = threadIdx.x;
    int v = (t < NBLK) ? bsum[t] : 0;
    sd[t] = v; __syncthreads();
    for (int off = 1; off < 256; off <<= 1) {
        int x = (t >= off) ? sd[t - off] : 0;
        __syncthreads();
        sd[t] += x;
        __syncthreads();
    }
    if (t < NBLK) bsum[t] = sd[t] - v;   // exclusive block offsets
    if (t == 0) row_ptr[NN] = NE;
}

__global__ void k_scan_chunks(const int* __restrict__ counts, const int* __restrict__ boff,
                              int* __restrict__ row_ptr) {
    __shared__ int sd[256];
    int t = threadIdx.x;
    int base = blockIdx.x * SCAN_CHUNK + t * 4;
    int c[4];
#pragma unroll
    for (int i = 0; i < 4; ++i) c[i] = (base + i < NN) ? counts[base + i] : 0;
    int tt = c[0] + c[1] + c[2] + c[3];
    sd[t] = tt; __syncthreads();
    for (int off = 1; off < 256; off <<= 1) {
        int x = (t >= off) ? sd[t - off] : 0;
        __syncthreads();
        sd[t] += x;
        __syncthreads();
    }
    int off0 = boff[blockIdx.x] + (sd[t] - tt);
    int run = 0;
#pragma unroll
    for (int i = 0; i < 4; ++i) {
        if (base + i < NN) row_ptr[base + i] = off0 + run;
        run += c[i];
    }
}

// ---------------------------------------------------------------- CSR fill (atomic-free)
// col[row_ptr[dst] + rank] = src. 8 edges/thread, no atomics in the chain.
__global__ void k_fill(const int4* __restrict__ src4, const int4* __restrict__ dst4,
                       const int4* __restrict__ rank4, const int* __restrict__ row_ptr,
                       int* __restrict__ col) {
    int t = blockIdx.x * blockDim.x + threadIdx.x;   // over NE/8
    if (t >= NE / 8) return;
    int4 s0 = src4[2 * t],  s1 = src4[2 * t + 1];
    int4 d0 = dst4[2 * t],  d1 = dst4[2 * t + 1];
    int4 r0 = rank4[2 * t], r1 = rank4[2 * t + 1];
    int p0 = row_ptr[d0.x], p1 = row_ptr[d0.y], p2 = row_ptr[d0.z], p3 = row_ptr[d0.w];
    int p4 = row_ptr[d1.x], p5 = row_ptr[d1.y], p6 = row_ptr[d1.z], p7 = row_ptr[d1.w];
    col[p0 + r0.x] = s0.x;
    col[p1 + r0.y] = s0.y;
    col[p2 + r0.z] = s0.z;
    col[p3 + r0.w] = s0.w;
    col[p4 + r1.x] = s1.x;
    col[p5 + r1.y] = s1.y;
    col[p6 + r1.z] = s1.z;
    col[p7 + r1.w] = s1.w;
}

// ---------------------------------------------------------------- aggregation (quad-gather)
// y[n] = fp16( dinv[n] * (xs[n] + sum_{s in N(n)} xs[s]) )
// Wave = 4 quads x 16 lanes. Each QUAD gathers a different neighbor row; a lane
// holds 4 half-features (uint2 = 8 B). One gather instruction moves 4 rows
// (512 B) vs 1 row (128 B) for lane=feature — 4x fewer memory instructions.
// 2 nodes/wave x 2 steps in flight = 16 rows outstanding. Tail slots gather the
// zeroed pad row NN. Epilogue: shfl_xor(16/32) cross-quad reduce; quads 0/1
// store the two fp16 rows in a single instruction.
__global__ __launch_bounds__(256) void k_aggregate(const __half* __restrict__ x,
                                                   __half* __restrict__ y,
                                                   const float* __restrict__ dinv,
                                                   const int* __restrict__ row_ptr,
                                                   const int* __restrict__ col) {
    int lane = threadIdx.x & 63;
    int wave = blockIdx.x * 4 + (threadIdx.x >> 6);
    int na = wave * 2;
    if (na >= NN) return;
    int nb = na + 1;                     // NN even: always valid
    int q  = lane >> 4;                  // quad 0..3 (row slot within a step)
    int f4 = (lane & 15) << 2;           // 4-feature base for this lane

    float a0 = 0.f, a1 = 0.f, a2 = 0.f, a3 = 0.f;
    float b0 = 0.f, b1 = 0.f, b2 = 0.f, b3 = 0.f;

#define GATHER(r, c0, c1, c2, c3)                                          \
    {                                                                      \
        uint2 raw = *(const uint2*)(x + (size_t)(r) * HH + f4);            \
        float2 f0 = __half22float2(*(__half2*)&raw.x);                     \
        float2 f1 = __half22float2(*(__half2*)&raw.y);                     \
        c0 += f0.x; c1 += f0.y; c2 += f1.x; c3 += f1.y;                    \
    }

    int ea = row_ptr[na], enda = row_ptr[na + 1];
    int eb = enda,        endb = row_ptr[nb + 1];   // rows adjacent

    // prologue step: quad 0 = self row, quads 1-3 = first 3 edges (pad -> NN)
    {
        int ia = ea + q - 1;
        int ib = eb + q - 1;
        int rA = (q == 0) ? na : ((ia < enda) ? col[ia] : NN);
        int rB = (q == 0) ? nb : ((ib < endb) ? col[ib] : NN);
        GATHER(rA, a0, a1, a2, a3);
        GATHER(rB, b0, b1, b2, b3);
        ea += 3; eb += 3;
    }
    // main loop: 8 edges per node per iteration (2 quad-steps each, padded)
    while (ea < enda || eb < endb) {
        int iA1 = ea + q,     iA2 = ea + 4 + q;
        int iB1 = eb + q,     iB2 = eb + 4 + q;
        int rA1 = (iA1 < enda) ? col[iA1] : NN;
        int rA2 = (iA2 < enda) ? col[iA2] : NN;
        int rB1 = (iB1 < endb) ? col[iB1] : NN;
        int rB2 = (iB2 < endb) ? col[iB2] : NN;
        GATHER(rA1, a0, a1, a2, a3);
        GATHER(rA2, a0, a1, a2, a3);
        GATHER(rB1, b0, b1, b2, b3);
        GATHER(rB2, b0, b1, b2, b3);
        ea += 8; eb += 8;
    }
#undef GATHER

    // cross-quad reduction: quads differ in lane bits 4,5
    a0 += __shfl_xor(a0, 16); a1 += __shfl_xor(a1, 16);
    a2 += __shfl_xor(a2, 16); a3 += __shfl_xor(a3, 16);
    b0 += __shfl_xor(b0, 16); b1 += __shfl_xor(b1, 16);
    b2 += __shfl_xor(b2, 16); b3 += __shfl_xor(b3, 16);
    a0 += __shfl_xor(a0, 32); a1 += __shfl_xor(a1, 32);
    a2 += __shfl_xor(a2, 32); a3 += __shfl_xor(a3, 32);
    b0 += __shfl_xor(b0, 32); b1 += __shfl_xor(b1, 32);
    b2 += __shfl_xor(b2, 32); b3 += __shfl_xor(b3, 32);

    // quads 0/1 store node a / node b rows (one 256-B store instruction)
    if (lane < 32) {
        int   n  = (q == 0) ? na : nb;
        float dv = dinv[n];
        float s0 = (q == 0) ? a0 : b0;
        float s1 = (q == 0) ? a1 : b1;
        float s2 = (q == 0) ? a2 : b2;
        float s3 = (q == 0) ? a3 : b3;
        __half2 h0 = __halves2half2(__float2half_rn(dv * s0), __float2half_rn(dv * s1));
        __half2 h1 = __halves2half2(__float2half_rn(dv * s2), __float2half_rn(dv * s3));
        uint2 packed;
        packed.x = *(unsigned int*)&h0;
        packed.y = *(unsigned int*)&h1;
        *(uint2*)(y + (size_t)n * HH + f4) = packed;
    }
}

// ---------------------------------------------------------------- GEMM: out = y @ W + b
// y is fp16 (aggregate output). 256 threads, 128 rows/block, 4x8 thread tile,
// W + y-tile (converted to fp32) in LDS.
// OutT=__half: writes NEXT layer's prescaled gather source fp16(dinv*(yW+b)).
// OutT=float:  final layer — split-write fp32 into d_out's two x slices.
#define GR 128
#define XSS 65   // +1 pad: conflict-free scalar broadcasts
template <typename OutT>
__global__ __launch_bounds__(256) void k_gemm(const __half* __restrict__ y,
                                              const float* __restrict__ W,
                                              const float* __restrict__ b,
                                              const float* __restrict__ dinv,
                                              OutT* __restrict__ out_lo,
                                              OutT* __restrict__ out_hi,
                                              int split) {
    __shared__ float xs[GR * XSS];   // 33.3 KB
    __shared__ float ws[HH * HH];    // 16 KB
    int t = threadIdx.x;
    int rowBase = blockIdx.x * GR;

    {   // stage W: 1024 float4 / 256 threads
        const float4* W4 = (const float4*)W;
        float4* ws4 = (float4*)ws;
#pragma unroll
        for (int i = 0; i < 4; ++i) ws4[i * 256 + t] = W4[i * 256 + t];
    }
    // stage y tile: 1024 8-half chunks / 256 threads, fp16 -> fp32 into LDS
#pragma unroll
    for (int it = 0; it < 4; ++it) {
        int g = it * 256 + t;        // 0..1023
        int r = g >> 3;
        int c0 = (g & 7) * 8;
        int row = rowBase + r;
        if (row < NN) {
            int4 raw = *(const int4*)(y + (size_t)row * HH + c0);   // 8 halves
            __half2 h0 = *(__half2*)&raw.x, h1 = *(__half2*)&raw.y;
            __half2 h2 = *(__half2*)&raw.z, h3 = *(__half2*)&raw.w;
            float2 f0 = __half22float2(h0), f1 = __half22float2(h1);
            float2 f2 = __half22float2(h2), f3 = __half22float2(h3);
            float* dp = xs + r * XSS + c0;
            dp[0] = f0.x; dp[1] = f0.y; dp[2] = f1.x; dp[3] = f1.y;
            dp[4] = f2.x; dp[5] = f2.y; dp[6] = f3.x; dp[7] = f3.y;
        }
    }
    __syncthreads();

    int tx = t & 7;        // 8 col-groups of 8
    int ty = t >> 3;       // 32 row-groups of 4
    int j0 = tx * 8;
    int r0 = ty * 4;

    float acc[4][8];
#pragma unroll
    for (int i = 0; i < 4; ++i)
#pragma unroll
        for (int j = 0; j < 8; ++j) acc[i][j] = 0.f;

    for (int k = 0; k < HH; ++k) {
        float4 w0 = *(const float4*)(ws + k * HH + j0);
        float4 w1 = *(const float4*)(ws + k * HH + j0 + 4);
        float wv[8] = {w0.x, w0.y, w0.z, w0.w, w1.x, w1.y, w1.z, w1.w};
#pragma unroll
        for (int i = 0; i < 4; ++i) {
            float xv = xs[(r0 + i) * XSS + k];
#pragma unroll
            for (int j = 0; j < 8; ++j) acc[i][j] += xv * wv[j];
        }
    }

    float bj[8];
#pragma unroll
    for (int j = 0; j < 8; ++j) bj[j] = b[j0 + j];

#pragma unroll
    for (int i = 0; i < 4; ++i) {
        int r = rowBase + r0 + i;
        if (r >= NN) continue;
        if constexpr (std::is_same_v<OutT, float>) {
            float4 o0 = make_float4(acc[i][0] + bj[0], acc[i][1] + bj[1],
                                    acc[i][2] + bj[2], acc[i][3] + bj[3]);
            float4 o1 = make_float4(acc[i][4] + bj[4], acc[i][5] + bj[5],
                                    acc[i][6] + bj[6], acc[i][7] + bj[7]);
            float* d = (r < split) ? ((float*)out_lo + (size_t)r * HH)
                                   : ((float*)out_hi + (size_t)(r - split) * HH);
            *(float4*)(d + j0) = o0;
            *(float4*)(d + j0 + 4) = o1;
        } else {
            float dv = dinv[r];   // prescale for next layer's gather source
            __half2 h[4];
#pragma unroll
            for (int j = 0; j < 4; ++j)
                h[j] = __halves2half2(
                    __float2half_rn((acc[i][2 * j]     + bj[2 * j])     * dv),
                    __float2half_rn((acc[i][2 * j + 1] + bj[2 * j + 1]) * dv));
            __half* d = (__half*)out_lo + (size_t)r * HH + j0;
            *(int4*)d = *(int4*)h;   // 16-B store
        }
    }
}

// ---------------------------------------------------------------- launch
extern "C" void kernel_launch(void* const* d_in, const int* in_sizes, int n_in,
                              void* d_out, int out_size, void* d_ws, size_t ws_size,
                              hipStream_t stream) {
    const int*   edge  = (const int*)d_in[0];
    const int*   src   = edge;           // edge_index[0]
    const int*   dst   = edge + NE;      // edge_index[1]
    const float* users = (const float*)d_in[1];
    const float* items = (const float*)d_in[2];
    const float* Ws    = (const float*)d_in[3];   // [3][64][64]
    const float* bs    = (const float*)d_in[4];   // [3][64]
    float*       out   = (float*)d_out;

    // workspace carve (~51 MB total). Xs buffers have NN+1 rows: row NN is a
    // zeroed pad row targeted by the aggregate's tail gathers.
    char* w = (char*)d_ws;
    __half* Xs0     = (__half*)w; w += (size_t)(NN + 1) * HH * 2;   // 19.2 MB
    __half* Xs1     = (__half*)w; w += (size_t)(NN + 1) * HH * 2;   // 19.2 MB
    float*  dinv    = (float*)w;  w += (size_t)NN * 4;
    int*    counts  = (int*)w;    w += (size_t)NN * 4;
    int*    row_ptr = (int*)w;    w += (size_t)(NN + 1) * 4;
    w += 4;                                                   // realign to 8
    int*    bsum    = (int*)w;    w += 256 * 4;
    int*    col     = (int*)w;    w += (size_t)NE * 4;        // 4.8 MB
    int*    rank    = (int*)w;    w += (size_t)NE * 4;        // 4.8 MB
    (void)ws_size; (void)in_sizes; (void)n_in; (void)out_size;

    hipMemsetAsync(counts, 0, (size_t)NN * sizeof(int), stream);
    hipMemsetAsync(Xs0 + (size_t)NN * HH, 0, HH * sizeof(__half), stream);  // pad row
    hipMemsetAsync(Xs1 + (size_t)NN * HH, 0, HH * sizeof(__half), stream);  // pad row

    k_rank<<<(NE / 4 + 255) / 256, 256, 0, stream>>>((const int4*)dst, counts, (int4*)rank);
    k_scan_reduce<<<NBLK, 256, 0, stream>>>(counts, bsum, dinv);
    k_concat<<<(NN * (HH / 4) + 255) / 256, 256, 0, stream>>>(
        (const float4*)users, (const float4*)items, dinv, (__half2*)Xs0, (float4*)out);
    k_scan_top<<<1, 256, 0, stream>>>(bsum, row_ptr);
    k_scan_chunks<<<NBLK, 256, 0, stream>>>(counts, bsum, row_ptr);
    k_fill<<<(NE / 8 + 255) / 256, 256, 0, stream>>>(
        (const int4*)src, (const int4*)dst, (const int4*)rank, row_ptr, col);

    // per layer: aggregate (Xs0 -> Xs1 fp16), gemm (Xs1 -> Xs0 / final out)
    const int AGG_BLOCKS  = NN / 8;                    // 2 nodes/wave, 4 waves/block
    const int GEMM_BLOCKS = (NN + GR - 1) / GR;

    k_aggregate<<<AGG_BLOCKS, 256, 0, stream>>>(Xs0, Xs1, dinv, row_ptr, col);
    k_gemm<__half><<<GEMM_BLOCKS, 256, 0, stream>>>(
        Xs1, Ws + 0 * HH * HH, bs + 0 * HH, dinv, Xs0, Xs0, NN);
    k_aggregate<<<AGG_BLOCKS, 256, 0, stream>>>(Xs0, Xs1, dinv, row_ptr, col);
    k_gemm<__half><<<GEMM_BLOCKS, 256, 0, stream>>>(
        Xs1, Ws + 1 * HH * HH, bs + 1 * HH, dinv, Xs0, Xs0, NN);
    k_aggregate<<<AGG_BLOCKS, 256, 0, stream>>>(Xs0, Xs1, dinv, row_ptr, col);
    k_gemm<float><<<GEMM_BLOCKS, 256, 0, stream>>>(
        Xs1, Ws + 2 * HH * HH, bs + 2 * HH, dinv,
        out /* x_users */, out + (size_t)2 * NU * HH /* x_items */, NU);
}